// Round 6
// baseline (676.679 us; speedup 1.0000x reference)
//
#include <hip/hip_runtime.h>
#include <hip/hip_fp16.h>

#define NN 30000
#define NE 480000
#define CC 32
#define TT 12
#define CT 384            /* C*T */
#define CT2 192           /* CT/2 half2 words per row */
#define GPB 4             /* nodes per block (gather + matmul) */
#define TOT (4 * NN)      /* 120000 */
#define NB  118           /* ceil(TOT/1024) */

typedef unsigned int u32x4 __attribute__((ext_vector_type(4)));

static __device__ __forceinline__ unsigned int pk_h2(float a, float b) {
    __half2 h = __floats2half2_rn(a, b);
    return __builtin_bit_cast(unsigned int, h);
}
static __device__ __forceinline__ unsigned int pk_add(unsigned int a, unsigned int b) {
    __half2 r = __hadd2(__builtin_bit_cast(__half2, a), __builtin_bit_cast(__half2, b));
    return __builtin_bit_cast(unsigned int, r);
}

// ---------------- x -> fp16, slice-affine (slice = blockIdx & 7 -> its XCD) ----------------
// xh row layout: [n][c][t] halves, 768 B/row; slice s = channels 4s..4s+3 = bytes [96s,96s+96)

__global__ void conv_kernel(const float2* __restrict__ x2, __half2* __restrict__ xh2) {
    const int slice = blockIdx.x & 7;
    const int nbase = (blockIdx.x >> 3) * 32;
#pragma unroll
    for (int step = 0; step < 3; ++step) {
        int e = step * 256 + threadIdx.x;          // e < 32*24
        int node = nbase + e / 24;
        int h = e % 24;                            // kk*6 + tp
        if (node < NN) {
            float2 v = x2[(size_t)node * 192 + slice * 24 + h];
            xh2[(size_t)node * 192 + slice * 24 + h] = __floats2half2_rn(v.x, v.y);
        }
    }
}

// ---------------- CSR build ----------------

__global__ void hist_kernel(const int* __restrict__ ei0, const int* __restrict__ ei1,
                            const int* __restrict__ ei2, const int* __restrict__ ei3,
                            int* __restrict__ cnt) {
    int e = blockIdx.x * blockDim.x + threadIdx.x;
    int b = blockIdx.y;
    if (e >= NE) return;
    const int* ei = (b == 0) ? ei0 : (b == 1) ? ei1 : (b == 2) ? ei2 : ei3;
    atomicAdd(&cnt[b * NN + ei[NE + e]], 1);   // dst row
}

__global__ void scanA_kernel(const int* __restrict__ cnt,
                             int* __restrict__ pre, int* __restrict__ bsum) {
    __shared__ int s[1024];
    int tid = threadIdx.x;
    int i = blockIdx.x * 1024 + tid;
    int v = (i < TOT) ? cnt[i] : 0;
    s[tid] = v;
    __syncthreads();
    for (int off = 1; off < 1024; off <<= 1) {
        int t = (tid >= off) ? s[tid - off] : 0;
        __syncthreads();
        s[tid] += t;
        __syncthreads();
    }
    if (i < TOT) pre[i] = s[tid] - v;
    if (tid == 1023) bsum[blockIdx.x] = s[1023];
}

__global__ void scanB_kernel(const int* __restrict__ bsum,
                             int* __restrict__ bbase, int* __restrict__ offs) {
    __shared__ int s[128];
    int tid = threadIdx.x;
    int v = (tid < NB) ? bsum[tid] : 0;
    s[tid] = v;
    __syncthreads();
    for (int off = 1; off < 128; off <<= 1) {
        int t = (tid >= off) ? s[tid - off] : 0;
        __syncthreads();
        s[tid] += t;
        __syncthreads();
    }
    if (tid < NB) bbase[tid] = s[tid] - v;
    if (tid == 127) offs[TOT] = s[127];
}

__global__ void scanC_kernel(const int* __restrict__ pre, const int* __restrict__ bbase,
                             int* __restrict__ offs, int* __restrict__ cur) {
    int i = blockIdx.x * 1024 + threadIdx.x;
    if (i < TOT) {
        int o = bbase[blockIdx.x] + pre[i];
        offs[i] = o;
        cur[i] = o;
    }
}

__global__ void scatter_kernel(const int* __restrict__ ei0, const int* __restrict__ ei1,
                               const int* __restrict__ ei2, const int* __restrict__ ei3,
                               const float* __restrict__ ew0, const float* __restrict__ ew1,
                               const float* __restrict__ ew2, const float* __restrict__ ew3,
                               int* __restrict__ cur, unsigned int* __restrict__ pairs) {
    int e = blockIdx.x * blockDim.x + threadIdx.x;
    int b = blockIdx.y;
    if (e >= NE) return;
    const int*   ei = (b == 0) ? ei0 : (b == 1) ? ei1 : (b == 2) ? ei2 : ei3;
    const float* ew = (b == 0) ? ew0 : (b == 1) ? ew1 : (b == 2) ? ew2 : ew3;
    int d = ei[NE + e];
    int pos = atomicAdd(&cur[b * NN + d], 1);
    unsigned int w16 = (unsigned int)__half_as_ushort(__float2half_rn(ew[e]));
    pairs[pos] = (unsigned int)ei[e] | (w16 << 16);
}

// ---------------- slice-affine gather ----------------
// block: 256 thr = 4 waves; wave = node (4 nodes/block); slice = blockIdx & 7.
// wave lanes: 8 edge-groups (g) x 8 byte-chunks (l, 12 B each) -> one 768-B load = 8 edges' slices.

__global__ __launch_bounds__(256, 8)
void gather_kernel(const char* __restrict__ xh, const unsigned int* __restrict__ pairs,
                   const int* __restrict__ offs, char* __restrict__ agg) {
    const int tid  = threadIdx.x;
    const int wave = tid >> 6;
    const int lane = tid & 63;
    const int slice = blockIdx.x & 7;
    const int n = (blockIdx.x >> 3) * GPB + wave;
    const int g = lane >> 3, l = lane & 7;
    const int sliceoff = slice * 96 + l * 12;

    int b0[4], c[4];
    unsigned int pv[4];
#pragma unroll
    for (int k = 0; k < 4; ++k) {
        const int row = __builtin_amdgcn_readfirstlane(k * NN + n);
        b0[k] = offs[row];
        c[k]  = offs[row + 1] - b0[k];
        pv[k] = (lane < c[k]) ? __builtin_nontemporal_load(pairs + b0[k] + lane) : 0u;
    }

#pragma unroll
    for (int k = 0; k < 4; ++k) {
        float a0 = 0.f, a1 = 0.f, a2 = 0.f, a3 = 0.f, a4 = 0.f, a5 = 0.f;
        const int cc = c[k];
        unsigned int pbuf = pv[k];
        int done = 0;
        for (;;) {
            const int m = min(cc - done, 64);
#pragma unroll 2
            for (int j = 0; j < m; j += 8) {
                unsigned int w32 = (unsigned int)__shfl((int)pbuf, j + g, 64);
                const char* rowp = xh + (size_t)(w32 & 0xFFFFu) * 768 + sliceoff;
                uint3 vv = *(const uint3*)rowp;
                float w = __half2float(__ushort_as_half((unsigned short)(w32 >> 16)));
                float2 f0 = __half22float2(*(const __half2*)&vv.x);
                float2 f1 = __half22float2(*(const __half2*)&vv.y);
                float2 f2 = __half22float2(*(const __half2*)&vv.z);
                a0 = fmaf(w, f0.x, a0); a1 = fmaf(w, f0.y, a1);
                a2 = fmaf(w, f1.x, a2); a3 = fmaf(w, f1.y, a3);
                a4 = fmaf(w, f2.x, a4); a5 = fmaf(w, f2.y, a5);
            }
            done += m;
            if (done >= cc) break;
            pbuf = (done + lane < cc) ? __builtin_nontemporal_load(pairs + b0[k] + done + lane) : 0u;
        }
        // pack to fp16 and xor-reduce across the 8 edge-groups (lane bits 3..5)
        unsigned int u0 = pk_h2(a0, a1);
        unsigned int u1 = pk_h2(a2, a3);
        unsigned int u2 = pk_h2(a4, a5);
#pragma unroll
        for (int d = 8; d < 64; d <<= 1) {
            u0 = pk_add(u0, (unsigned int)__shfl_xor((int)u0, d, 64));
            u1 = pk_add(u1, (unsigned int)__shfl_xor((int)u1, d, 64));
            u2 = pk_add(u2, (unsigned int)__shfl_xor((int)u2, d, 64));
        }
        if (lane < 8) {
            char* dst = agg + (size_t)(k * NN + n) * 768 + slice * 96 + lane * 12;
            __builtin_nontemporal_store(u0, (unsigned int*)dst);
            __builtin_nontemporal_store(u1, (unsigned int*)(dst + 4));
            __builtin_nontemporal_store(u2, (unsigned int*)(dst + 8));
        }
    }
}

// ---------------- streaming matmul: out = bias + sum_b agg_b @ W_b ----------------

__global__ __launch_bounds__(256, 8)
void matmul_kernel(const char* __restrict__ agg,
                   const float* __restrict__ W0, const float* __restrict__ W1,
                   const float* __restrict__ W2, const float* __restrict__ W3,
                   const float* __restrict__ bias, float* __restrict__ out) {
    __shared__ char aggB[16 * 768];   // 12 KB
    const int tid = threadIdx.x;
    const int n0 = blockIdx.x * GPB;

    // stage 16 rows (r = g*4+b  ->  global row b*NN + n0+g); 16 thr/row x 48 B
    {
        const int r = tid >> 4, sub = tid & 15;
        const char* src = agg + (size_t)((r & 3) * NN + n0 + (r >> 2)) * 768 + sub * 48;
        char* dst = aggB + r * 768 + sub * 48;
        u32x4 q0 = __builtin_nontemporal_load((const u32x4*)(src));
        u32x4 q1 = __builtin_nontemporal_load((const u32x4*)(src + 16));
        u32x4 q2 = __builtin_nontemporal_load((const u32x4*)(src + 32));
        *(u32x4*)dst = q0; *(u32x4*)(dst + 16) = q1; *(u32x4*)(dst + 32) = q2;
    }
    __syncthreads();

    const __half* __restrict__ aggH = (const __half*)aggB;
    const float* Ws[4] = { W0, W1, W2, W3 };
    for (int slot = tid; slot < GPB * 96; slot += 256) {
        int gg = slot / 96;
        int rem = slot % 96;
        int q = rem / TT;       // 0..7
        int t = rem % TT;       // 0..11
        float acc[4];
#pragma unroll
        for (int i = 0; i < 4; ++i) acc[i] = bias[q * 4 + i];
#pragma unroll
        for (int b = 0; b < 4; ++b) {
            const float* __restrict__ Wb = Ws[b];
            const __half* __restrict__ aL = &aggH[(gg * 4 + b) * CT];
#pragma unroll
            for (int h = 0; h < 2; ++h) {
                float row[16];
#pragma unroll
                for (int kk = 0; kk < 16; ++kk)
                    row[kk] = __half2float(aL[(h * 16 + kk) * TT + t]);
#pragma unroll
                for (int kk = 0; kk < 16; ++kk) {
#pragma unroll
                    for (int i = 0; i < 4; ++i)
                        acc[i] = fmaf(row[kk], Wb[(h * 16 + kk) * CC + q * 4 + i], acc[i]);
                }
            }
        }
#pragma unroll
        for (int i = 0; i < 4; ++i)
            __builtin_nontemporal_store(acc[i], &out[(size_t)(n0 + gg) * CT + (q * 4 + i) * TT + t]);
    }
}

// ---------------- launch ----------------

extern "C" void kernel_launch(void* const* d_in, const int* in_sizes, int n_in,
                              void* d_out, int out_size, void* d_ws, size_t ws_size,
                              hipStream_t stream) {
    const float* x    = (const float*)d_in[0];
    const float* bias = (const float*)d_in[13];
    const int*   ei[4] = { (const int*)d_in[1], (const int*)d_in[4],
                           (const int*)d_in[7], (const int*)d_in[10] };
    const float* ew[4] = { (const float*)d_in[2], (const float*)d_in[5],
                           (const float*)d_in[8], (const float*)d_in[11] };
    const float* W[4]  = { (const float*)d_in[3], (const float*)d_in[6],
                           (const float*)d_in[9], (const float*)d_in[12] };
    float* out = (float*)d_out;

    char* ws = (char*)d_ws;
    size_t OFF_PAIRS = 0;                                     // 4E u32   = 7.68 MB
    size_t OFF_XH    = OFF_PAIRS + (size_t)4 * NE * 4;        // 23.04 MB fp16 x
    size_t OFF_AGG   = OFF_XH    + (size_t)NN * 768;          // 92.16 MB fp16 agg
    size_t OFF_CNT   = OFF_AGG   + (size_t)TOT * 768;         // TOT int
    size_t OFF_OFFS  = OFF_CNT   + (size_t)TOT * 4;           // TOT+1 int
    size_t OFF_CUR   = OFF_OFFS  + (size_t)(TOT + 1) * 4;     // TOT int
    size_t OFF_PRE   = OFF_CUR   + (size_t)TOT * 4;           // TOT int
    size_t OFF_BSUM  = OFF_PRE   + (size_t)TOT * 4;           // 128 int
    size_t OFF_BBASE = OFF_BSUM  + (size_t)128 * 4;           // 128 int

    unsigned int* pairs = (unsigned int*)(ws + OFF_PAIRS);
    char*         xh    = ws + OFF_XH;
    char*         agg   = ws + OFF_AGG;
    int* cnt   = (int*)(ws + OFF_CNT);
    int* offs  = (int*)(ws + OFF_OFFS);
    int* cur   = (int*)(ws + OFF_CUR);
    int* pre   = (int*)(ws + OFF_PRE);
    int* bsum  = (int*)(ws + OFF_BSUM);
    int* bbase = (int*)(ws + OFF_BBASE);

    hipMemsetAsync(cnt, 0, (size_t)TOT * 4, stream);

    dim3 eg((NE + 255) / 256, 4);
    hist_kernel<<<eg, 256, 0, stream>>>(ei[0], ei[1], ei[2], ei[3], cnt);
    scanA_kernel<<<NB, 1024, 0, stream>>>(cnt, pre, bsum);
    scanB_kernel<<<1, 128, 0, stream>>>(bsum, bbase, offs);
    scanC_kernel<<<NB, 1024, 0, stream>>>(pre, bbase, offs, cur);
    scatter_kernel<<<eg, 256, 0, stream>>>(ei[0], ei[1], ei[2], ei[3],
                                           ew[0], ew[1], ew[2], ew[3],
                                           cur, pairs);

    // conv AFTER the build kernels so each XCD's L2 is warm with its slice
    conv_kernel<<<((NN + 31) / 32) * 8, 256, 0, stream>>>((const float2*)x, (__half2*)xh);

    gather_kernel<<<(NN / GPB) * 8, 256, 0, stream>>>(xh, pairs, offs, agg);

    matmul_kernel<<<NN / GPB, 256, 0, stream>>>(agg, W[0], W[1], W[2], W[3], bias, out);
}

// Round 9
// 569.734 us; speedup vs baseline: 1.1877x; 1.1877x over previous
//
#include <hip/hip_runtime.h>
#include <hip/hip_fp16.h>

#define NN 30000
#define NE 480000
#define CC 32
#define TT 12
#define CT 384            /* C*T */
#define GPB 4             /* nodes per block (gather + matmul) */
#define TOT (4 * NN)      /* 120000 */
#define NB  118           /* ceil(TOT/1024) */
#define SLICE_BYTES ((size_t)NN * 96)   /* 2.88 MB per 4-channel slice */
#define RSH2 193          /* matmul LDS row stride in half2 (padded) */

typedef unsigned int u32x4 __attribute__((ext_vector_type(4)));
typedef float f32x2 __attribute__((ext_vector_type(2)));

static __device__ __forceinline__ unsigned int pk_add(unsigned int a, unsigned int b) {
    __half2 r = __hadd2(__builtin_bit_cast(__half2, a), __builtin_bit_cast(__half2, b));
    return __builtin_bit_cast(unsigned int, r);
}

// ---------------- x -> fp16, slice-major layout ----------------
// slice s holds channels 4s..4s+3: xh_s[n][c&3][t] halves, 96 B (24 half2) per node.

__global__ void conv_kernel(const float2* __restrict__ x2, char* __restrict__ xh) {
    int i = blockIdx.x * blockDim.x + threadIdx.x;
    if (i < NN * 192) {
        float2 v = x2[i];
        int n = i / 192, w = i % 192;     // w = c*6 + tp
        int c = w / 6, tp = w % 6;
        __half2* dst = (__half2*)(xh + (size_t)(c >> 2) * SLICE_BYTES);
        dst[n * 24 + (c & 3) * 6 + tp] = __floats2half2_rn(v.x, v.y);
    }
}

// ---------------- CSR build ----------------

__global__ void hist_kernel(const int* __restrict__ ei0, const int* __restrict__ ei1,
                            const int* __restrict__ ei2, const int* __restrict__ ei3,
                            int* __restrict__ cnt) {
    int e = blockIdx.x * blockDim.x + threadIdx.x;
    int b = blockIdx.y;
    if (e >= NE) return;
    const int* ei = (b == 0) ? ei0 : (b == 1) ? ei1 : (b == 2) ? ei2 : ei3;
    atomicAdd(&cnt[b * NN + ei[NE + e]], 1);   // dst row
}

__global__ void scanA_kernel(const int* __restrict__ cnt,
                             int* __restrict__ pre, int* __restrict__ bsum) {
    __shared__ int s[1024];
    int tid = threadIdx.x;
    int i = blockIdx.x * 1024 + tid;
    int v = (i < TOT) ? cnt[i] : 0;
    s[tid] = v;
    __syncthreads();
    for (int off = 1; off < 1024; off <<= 1) {
        int t = (tid >= off) ? s[tid - off] : 0;
        __syncthreads();
        s[tid] += t;
        __syncthreads();
    }
    if (i < TOT) pre[i] = s[tid] - v;
    if (tid == 1023) bsum[blockIdx.x] = s[1023];
}

__global__ void scanB_kernel(const int* __restrict__ bsum,
                             int* __restrict__ bbase, int* __restrict__ offs) {
    __shared__ int s[128];
    int tid = threadIdx.x;
    int v = (tid < NB) ? bsum[tid] : 0;
    s[tid] = v;
    __syncthreads();
    for (int off = 1; off < 128; off <<= 1) {
        int t = (tid >= off) ? s[tid - off] : 0;
        __syncthreads();
        s[tid] += t;
        __syncthreads();
    }
    if (tid < NB) bbase[tid] = s[tid] - v;
    if (tid == 127) offs[TOT] = s[127];
}

__global__ void scanC_kernel(const int* __restrict__ pre, const int* __restrict__ bbase,
                             int* __restrict__ offs, int* __restrict__ cur) {
    int i = blockIdx.x * 1024 + threadIdx.x;
    if (i < TOT) {
        int o = bbase[blockIdx.x] + pre[i];
        offs[i] = o;
        cur[i] = o;
    }
}

__global__ void scatter_kernel(const int* __restrict__ ei0, const int* __restrict__ ei1,
                               const int* __restrict__ ei2, const int* __restrict__ ei3,
                               const float* __restrict__ ew0, const float* __restrict__ ew1,
                               const float* __restrict__ ew2, const float* __restrict__ ew3,
                               int* __restrict__ cur, unsigned int* __restrict__ pairs) {
    int e = blockIdx.x * blockDim.x + threadIdx.x;
    int b = blockIdx.y;
    if (e >= NE) return;
    const int*   ei = (b == 0) ? ei0 : (b == 1) ? ei1 : (b == 2) ? ei2 : ei3;
    const float* ew = (b == 0) ? ew0 : (b == 1) ? ew1 : (b == 2) ? ew2 : ew3;
    int d = ei[NE + e];
    int pos = atomicAdd(&cur[b * NN + d], 1);
    unsigned int w16 = (unsigned int)__half_as_ushort(__float2half_rn(ew[e]));
    pairs[pos] = (unsigned int)ei[e] | (w16 << 16);
}

// ---------------- slice-resident gather ----------------
// grid (NN/GPB, 8): blockIdx.y = slice (slowest-varying -> one slice in flight chip-wide).
// block: 4 waves, wave = node. Wave lanes: 8 edge-groups x 8 chunks (12 B).

__global__ __launch_bounds__(256, 8)
void gather_kernel(const char* __restrict__ xh, const unsigned int* __restrict__ pairs,
                   const int* __restrict__ offs, char* __restrict__ agg) {
    const int tid  = threadIdx.x;
    const int wave = tid >> 6;
    const int lane = tid & 63;
    const int slice = blockIdx.y;
    const int n = blockIdx.x * GPB + wave;
    const int g = lane >> 3, l = lane & 7;
    const char* __restrict__ xs = xh + (size_t)slice * SLICE_BYTES + l * 12;

    int b0[4], c[4];
    unsigned int pv[4];
#pragma unroll
    for (int k = 0; k < 4; ++k) {
        const int row = __builtin_amdgcn_readfirstlane(k * NN + n);
        b0[k] = offs[row];
        c[k]  = offs[row + 1] - b0[k];
        pv[k] = (lane < c[k]) ? __builtin_nontemporal_load(pairs + b0[k] + lane) : 0u;
    }

#pragma unroll
    for (int k = 0; k < 4; ++k) {
        __half2 h0 = __half2(0.f, 0.f), h1 = __half2(0.f, 0.f), h2 = __half2(0.f, 0.f);
        const int cc = c[k];
        unsigned int pbuf = pv[k];
        int done = 0;
        for (;;) {
            const int m = min(cc - done, 64);
#pragma unroll 2
            for (int j = 0; j < m; j += 8) {
                unsigned int w32 = (unsigned int)__shfl((int)pbuf, j + g, 64);
                const char* rowp = xs + (w32 & 0xFFFFu) * 96;
                uint3 vv = *(const uint3*)rowp;
                __half2 w2 = __half2half2(__ushort_as_half((unsigned short)(w32 >> 16)));
                h0 = __hfma2(w2, __builtin_bit_cast(__half2, vv.x), h0);
                h1 = __hfma2(w2, __builtin_bit_cast(__half2, vv.y), h1);
                h2 = __hfma2(w2, __builtin_bit_cast(__half2, vv.z), h2);
            }
            done += m;
            if (done >= cc) break;
            pbuf = (done + lane < cc) ? __builtin_nontemporal_load(pairs + b0[k] + done + lane) : 0u;
        }
        // reduce across the 8 edge-groups (lane bits 3..5)
        unsigned int u0 = __builtin_bit_cast(unsigned int, h0);
        unsigned int u1 = __builtin_bit_cast(unsigned int, h1);
        unsigned int u2 = __builtin_bit_cast(unsigned int, h2);
#pragma unroll
        for (int d = 8; d < 64; d <<= 1) {
            u0 = pk_add(u0, (unsigned int)__shfl_xor((int)u0, d, 64));
            u1 = pk_add(u1, (unsigned int)__shfl_xor((int)u1, d, 64));
            u2 = pk_add(u2, (unsigned int)__shfl_xor((int)u2, d, 64));
        }
        if (lane < 8) {
            char* dst = agg + (size_t)(k * NN + n) * 768 + slice * 96 + lane * 12;
            __builtin_nontemporal_store(u0, (unsigned int*)dst);
            __builtin_nontemporal_store(u1, (unsigned int*)(dst + 4));
            __builtin_nontemporal_store(u2, (unsigned int*)(dst + 8));
        }
    }
}

// ---------------- streaming matmul: out = bias + sum_b agg_b @ W_b ----------------
// agg row (branch,node): [c][t] halves, 768 B. LDS staged with padded stride RSH2 half2.

__global__ __launch_bounds__(256, 8)
void matmul_kernel(const char* __restrict__ agg,
                   const float* __restrict__ W0, const float* __restrict__ W1,
                   const float* __restrict__ W2, const float* __restrict__ W3,
                   const float* __restrict__ bias, float* __restrict__ out) {
    __shared__ __half2 aggB[16 * RSH2];   // ~12.4 KB
    const int tid = threadIdx.x;
    const int n0 = blockIdx.x * GPB;

    // stage 16 rows (r = g*4+b -> global row b*NN + n0+g); 16 thr/row x 48 B
    {
        const int r = tid >> 4, sub = tid & 15;
        const char* src = agg + (size_t)((r & 3) * NN + n0 + (r >> 2)) * 768 + sub * 48;
        char* dst = (char*)(aggB + r * RSH2) + sub * 48;
        u32x4 q0 = __builtin_nontemporal_load((const u32x4*)(src));
        u32x4 q1 = __builtin_nontemporal_load((const u32x4*)(src + 16));
        u32x4 q2 = __builtin_nontemporal_load((const u32x4*)(src + 32));
        *(u32x4*)dst = q0; *(u32x4*)(dst + 16) = q1; *(u32x4*)(dst + 32) = q2;
    }
    __syncthreads();

    const float* Ws[4] = { W0, W1, W2, W3 };
    // slot = (g, q, t2): 4*8*6 = 192 slots; each computes 4 channels x 2 t.
    if (tid < 192) {
        const int g = tid / 48;
        const int rem = tid % 48;
        const int q = rem / 6;        // 0..7  -> channels 4q..4q+3
        const int t2 = rem % 6;       // 0..5  -> t = 2*t2, 2*t2+1
        f32x2 acc[4];
#pragma unroll
        for (int i = 0; i < 4; ++i) { float bv = bias[q * 4 + i]; acc[i].x = bv; acc[i].y = bv; }
#pragma unroll
        for (int b = 0; b < 4; ++b) {
            const float* __restrict__ Wb = Ws[b];
            const __half2* __restrict__ aL = aggB + (g * 4 + b) * RSH2 + t2;
#pragma unroll
            for (int h = 0; h < 2; ++h) {
                float2 row[16];
#pragma unroll
                for (int kk = 0; kk < 16; ++kk)
                    row[kk] = __half22float2(aL[(h * 16 + kk) * 6]);
#pragma unroll
                for (int kk = 0; kk < 16; ++kk) {
#pragma unroll
                    for (int i = 0; i < 4; ++i) {
                        float w = Wb[(h * 16 + kk) * CC + q * 4 + i];
                        acc[i].x = fmaf(w, row[kk].x, acc[i].x);
                        acc[i].y = fmaf(w, row[kk].y, acc[i].y);
                    }
                }
            }
        }
#pragma unroll
        for (int i = 0; i < 4; ++i) {
            f32x2* dst = (f32x2*)&out[(size_t)(n0 + g) * CT + (q * 4 + i) * TT + 2 * t2];
            __builtin_nontemporal_store(acc[i], dst);
        }
    }
}

// ---------------- launch ----------------

extern "C" void kernel_launch(void* const* d_in, const int* in_sizes, int n_in,
                              void* d_out, int out_size, void* d_ws, size_t ws_size,
                              hipStream_t stream) {
    const float* x    = (const float*)d_in[0];
    const float* bias = (const float*)d_in[13];
    const int*   ei[4] = { (const int*)d_in[1], (const int*)d_in[4],
                           (const int*)d_in[7], (const int*)d_in[10] };
    const float* ew[4] = { (const float*)d_in[2], (const float*)d_in[5],
                           (const float*)d_in[8], (const float*)d_in[11] };
    const float* W[4]  = { (const float*)d_in[3], (const float*)d_in[6],
                           (const float*)d_in[9], (const float*)d_in[12] };
    float* out = (float*)d_out;

    char* ws = (char*)d_ws;
    size_t OFF_PAIRS = 0;                                     // 4E u32   = 7.68 MB
    size_t OFF_XH    = OFF_PAIRS + (size_t)4 * NE * 4;        // 23.04 MB fp16 x (slice-major)
    size_t OFF_AGG   = OFF_XH    + 8 * SLICE_BYTES;           // 92.16 MB fp16 agg
    size_t OFF_CNT   = OFF_AGG   + (size_t)TOT * 768;         // TOT int
    size_t OFF_OFFS  = OFF_CNT   + (size_t)TOT * 4;           // TOT+1 int
    size_t OFF_CUR   = OFF_OFFS  + (size_t)(TOT + 1) * 4;     // TOT int
    size_t OFF_PRE   = OFF_CUR   + (size_t)TOT * 4;           // TOT int
    size_t OFF_BSUM  = OFF_PRE   + (size_t)TOT * 4;           // 128 int
    size_t OFF_BBASE = OFF_BSUM  + (size_t)128 * 4;           // 128 int

    unsigned int* pairs = (unsigned int*)(ws + OFF_PAIRS);
    char*         xh    = ws + OFF_XH;
    char*         agg   = ws + OFF_AGG;
    int* cnt   = (int*)(ws + OFF_CNT);
    int* offs  = (int*)(ws + OFF_OFFS);
    int* cur   = (int*)(ws + OFF_CUR);
    int* pre   = (int*)(ws + OFF_PRE);
    int* bsum  = (int*)(ws + OFF_BSUM);
    int* bbase = (int*)(ws + OFF_BBASE);

    hipMemsetAsync(cnt, 0, (size_t)TOT * 4, stream);

    dim3 eg((NE + 255) / 256, 4);
    hist_kernel<<<eg, 256, 0, stream>>>(ei[0], ei[1], ei[2], ei[3], cnt);
    scanA_kernel<<<NB, 1024, 0, stream>>>(cnt, pre, bsum);
    scanB_kernel<<<1, 128, 0, stream>>>(bsum, bbase, offs);
    scanC_kernel<<<NB, 1024, 0, stream>>>(pre, bbase, offs, cur);
    scatter_kernel<<<eg, 256, 0, stream>>>(ei[0], ei[1], ei[2], ei[3],
                                           ew[0], ew[1], ew[2], ew[3],
                                           cur, pairs);

    conv_kernel<<<(NN * 192 + 255) / 256, 256, 0, stream>>>((const float2*)x, xh);

    dim3 gg(NN / GPB, 8);
    gather_kernel<<<gg, 256, 0, stream>>>(xh, pairs, offs, agg);

    matmul_kernel<<<NN / GPB, 256, 0, stream>>>(agg, W[0], W[1], W[2], W[3], bias, out);
}

// Round 10
// 458.877 us; speedup vs baseline: 1.4746x; 1.2416x over previous
//
#include <hip/hip_runtime.h>
#include <hip/hip_fp16.h>

#define NN 30000
#define NE 480000
#define CC 32
#define TT 12
#define CT 384            /* C*T */
#define TOT (4 * NN)      /* 120000 tasks */
#define NB  118           /* ceil(TOT/1024) */
#define NSL 6             /* slices per row */
#define SLB ((size_t)NN * 128)   /* 3.84 MB per 128-B slice array */
#define GPB 8             /* nodes per gather block */
#define GPM 8             /* nodes per matmul block */
#define RSH2 193          /* matmul LDS row stride in half2 (padded) */

typedef unsigned int u32x4 __attribute__((ext_vector_type(4)));
typedef float f32x2 __attribute__((ext_vector_type(2)));

static __device__ __forceinline__ unsigned int h2u(__half2 h) {
    return __builtin_bit_cast(unsigned int, h);
}
static __device__ __forceinline__ __half2 u2h(unsigned int u) {
    return __builtin_bit_cast(__half2, u);
}

// ---------------- x -> fp16, slice-major (6 slices x 128 B per node row) ----------------
// half index h = c*12+t in [0,384); slice s = h>>6; within-slice: node*32 + ((h/2)&31) half2.

__global__ void conv_kernel(const float2* __restrict__ x2, char* __restrict__ xh) {
    int i = blockIdx.x * blockDim.x + threadIdx.x;
    if (i < NN * 192) {
        float2 v = x2[i];
        int n = i / 192, w = i % 192;            // w = half2 index within row (h = 2w)
        __half2* dst = (__half2*)(xh + (size_t)(w >> 5) * SLB);
        dst[n * 32 + (w & 31)] = __floats2half2_rn(v.x, v.y);
    }
}

// ---------------- CSR build (offsets padded to multiples of 4 words) ----------------

__global__ void hist_kernel(const int* __restrict__ ei0, const int* __restrict__ ei1,
                            const int* __restrict__ ei2, const int* __restrict__ ei3,
                            int* __restrict__ cnt) {
    int e = blockIdx.x * blockDim.x + threadIdx.x;
    int b = blockIdx.y;
    if (e >= NE) return;
    const int* ei = (b == 0) ? ei0 : (b == 1) ? ei1 : (b == 2) ? ei2 : ei3;
    atomicAdd(&cnt[b * NN + ei[NE + e]], 1);   // dst row
}

__global__ void scanA_kernel(const int* __restrict__ cnt,
                             int* __restrict__ pre, int* __restrict__ bsum) {
    __shared__ int s[1024];
    int tid = threadIdx.x;
    int i = blockIdx.x * 1024 + tid;
    int v = (i < TOT) ? ((cnt[i] + 3) & ~3) : 0;   // padded counts
    s[tid] = v;
    __syncthreads();
    for (int off = 1; off < 1024; off <<= 1) {
        int t = (tid >= off) ? s[tid - off] : 0;
        __syncthreads();
        s[tid] += t;
        __syncthreads();
    }
    if (i < TOT) pre[i] = s[tid] - v;
    if (tid == 1023) bsum[blockIdx.x] = s[1023];
}

__global__ void scanB_kernel(const int* __restrict__ bsum,
                             int* __restrict__ bbase, int* __restrict__ offs) {
    __shared__ int s[128];
    int tid = threadIdx.x;
    int v = (tid < NB) ? bsum[tid] : 0;
    s[tid] = v;
    __syncthreads();
    for (int off = 1; off < 128; off <<= 1) {
        int t = (tid >= off) ? s[tid - off] : 0;
        __syncthreads();
        s[tid] += t;
        __syncthreads();
    }
    if (tid < NB) bbase[tid] = s[tid] - v;
    if (tid == 127) offs[TOT] = s[127];
}

__global__ void scanC_kernel(const int* __restrict__ pre, const int* __restrict__ bbase,
                             int* __restrict__ offs, int* __restrict__ cur) {
    int i = blockIdx.x * 1024 + threadIdx.x;
    if (i < TOT) {
        int o = bbase[blockIdx.x] + pre[i];
        offs[i] = o;
        cur[i] = o;
    }
}

__global__ void scatter_kernel(const int* __restrict__ ei0, const int* __restrict__ ei1,
                               const int* __restrict__ ei2, const int* __restrict__ ei3,
                               const float* __restrict__ ew0, const float* __restrict__ ew1,
                               const float* __restrict__ ew2, const float* __restrict__ ew3,
                               int* __restrict__ cur, unsigned int* __restrict__ pairs) {
    int e = blockIdx.x * blockDim.x + threadIdx.x;
    int b = blockIdx.y;
    if (e >= NE) return;
    const int*   ei = (b == 0) ? ei0 : (b == 1) ? ei1 : (b == 2) ? ei2 : ei3;
    const float* ew = (b == 0) ? ew0 : (b == 1) ? ew1 : (b == 2) ? ew2 : ew3;
    int d = ei[NE + e];
    int pos = atomicAdd(&cur[b * NN + d], 1);
    unsigned int w16 = (unsigned int)__half_as_ushort(__float2half_rn(ew[e]));
    pairs[pos] = (unsigned int)ei[e] | (w16 << 16);
}

// ---------------- slice-resident gather, octet-per-task, reduction-free ----------------
// grid (NN/GPB, NSL): blockIdx.y = slice (slowest-varying -> one 3.84 MB slice in flight).
// wave = 8 octets; octet -> task (node, branch); lane l in octet owns 16 B of the 128-B slice.

__global__ __launch_bounds__(256, 8)
void gather_kernel(const char* __restrict__ xh, const unsigned int* __restrict__ pairs,
                   const int* __restrict__ offs, const int* __restrict__ cnt,
                   char* __restrict__ agg) {
    const int tid  = threadIdx.x;
    const int lane = tid & 63;
    const int o = lane >> 3, l = lane & 7;
    const int task = (tid >> 6) * 8 + o;                 // 0..31
    const int node = blockIdx.x * GPB + (task >> 2);
    const int branch = task & 3;
    const int row = branch * NN + node;
    const int slice = blockIdx.y;
    const char* __restrict__ xs = xh + (size_t)slice * SLB + l * 16;

    const int beg = offs[row];
    const int c   = cnt[row];

    // dual accumulator sets (even/odd u) halve the fp16 chain length
    __half2 a0 = u2h(0), a1 = u2h(0), a2 = u2h(0), a3 = u2h(0);
    __half2 b0 = u2h(0), b1 = u2h(0), b2 = u2h(0), b3 = u2h(0);

    for (int eb = 0; eb < c; eb += 4) {
        u32x4 pw = *(const u32x4*)(pairs + beg + eb);    // aligned: beg%4==0
#pragma unroll
        for (int u = 0; u < 4; ++u) {
            unsigned int w32 = (u == 0) ? pw.x : (u == 1) ? pw.y : (u == 2) ? pw.z : pw.w;
            if (eb + u < c) {
                u32x4 xv = *(const u32x4*)(xs + (size_t)(w32 & 0xFFFFu) * 128);
                __half2 w2 = __half2half2(__ushort_as_half((unsigned short)(w32 >> 16)));
                if (u & 1) {
                    b0 = __hfma2(w2, u2h(xv.x), b0);
                    b1 = __hfma2(w2, u2h(xv.y), b1);
                    b2 = __hfma2(w2, u2h(xv.z), b2);
                    b3 = __hfma2(w2, u2h(xv.w), b3);
                } else {
                    a0 = __hfma2(w2, u2h(xv.x), a0);
                    a1 = __hfma2(w2, u2h(xv.y), a1);
                    a2 = __hfma2(w2, u2h(xv.z), a2);
                    a3 = __hfma2(w2, u2h(xv.w), a3);
                }
            }
        }
    }
    u32x4 r;
    r.x = h2u(__hadd2(a0, b0));
    r.y = h2u(__hadd2(a1, b1));
    r.z = h2u(__hadd2(a2, b2));
    r.w = h2u(__hadd2(a3, b3));
    __builtin_nontemporal_store(r, (u32x4*)(agg + (size_t)row * 768 + slice * 128 + l * 16));
}

// ---------------- streaming matmul: out = bias + sum_b agg_b @ W_b ----------------

__global__ __launch_bounds__(384)
void matmul_kernel(const char* __restrict__ agg,
                   const float* __restrict__ W0, const float* __restrict__ W1,
                   const float* __restrict__ W2, const float* __restrict__ W3,
                   const float* __restrict__ bias, float* __restrict__ out) {
    __shared__ __half2 aggB[32 * RSH2];   // ~24.7 KB
    const int tid = threadIdx.x;
    const int n0 = blockIdx.x * GPM;

    // stage 32 rows (r = g*4+b -> global row b*NN + n0+g); 12 thr/row x 64 B
    {
        const int r = tid / 12, sub = tid % 12;
        const char* src = agg + (size_t)((r & 3) * NN + n0 + (r >> 2)) * 768 + sub * 64;
        char* dst = (char*)(aggB + r * RSH2) + sub * 64;
#pragma unroll
        for (int q = 0; q < 4; ++q) {
            u32x4 v = __builtin_nontemporal_load((const u32x4*)(src + 16 * q));
            *(u32x4*)(dst + 16 * q) = v;
        }
    }
    __syncthreads();

    const float* Ws[4] = { W0, W1, W2, W3 };
    // slot = tid: g = tid/48 (0..7), q = (tid%48)/6, t2 = tid%6; 4 channels x 2 t each.
    {
        const int g = tid / 48;
        const int rem = tid % 48;
        const int q = rem / 6;
        const int t2 = rem % 6;
        f32x2 acc[4];
#pragma unroll
        for (int i = 0; i < 4; ++i) { float bv = bias[q * 4 + i]; acc[i].x = bv; acc[i].y = bv; }
#pragma unroll
        for (int b = 0; b < 4; ++b) {
            const float* __restrict__ Wb = Ws[b];
            const __half2* __restrict__ aL = aggB + (g * 4 + b) * RSH2 + t2;
#pragma unroll
            for (int h = 0; h < 2; ++h) {
                float2 row[16];
#pragma unroll
                for (int kk = 0; kk < 16; ++kk)
                    row[kk] = __half22float2(aL[(h * 16 + kk) * 6]);
#pragma unroll
                for (int kk = 0; kk < 16; ++kk) {
#pragma unroll
                    for (int i = 0; i < 4; ++i) {
                        float w = Wb[(h * 16 + kk) * CC + q * 4 + i];
                        acc[i].x = fmaf(w, row[kk].x, acc[i].x);
                        acc[i].y = fmaf(w, row[kk].y, acc[i].y);
                    }
                }
            }
        }
#pragma unroll
        for (int i = 0; i < 4; ++i) {
            f32x2* dst = (f32x2*)&out[(size_t)(n0 + g) * CT + (q * 4 + i) * TT + 2 * t2];
            __builtin_nontemporal_store(acc[i], dst);
        }
    }
}

// ---------------- launch ----------------

extern "C" void kernel_launch(void* const* d_in, const int* in_sizes, int n_in,
                              void* d_out, int out_size, void* d_ws, size_t ws_size,
                              hipStream_t stream) {
    const float* x    = (const float*)d_in[0];
    const float* bias = (const float*)d_in[13];
    const int*   ei[4] = { (const int*)d_in[1], (const int*)d_in[4],
                           (const int*)d_in[7], (const int*)d_in[10] };
    const float* ew[4] = { (const float*)d_in[2], (const float*)d_in[5],
                           (const float*)d_in[8], (const float*)d_in[11] };
    const float* W[4]  = { (const float*)d_in[3], (const float*)d_in[6],
                           (const float*)d_in[9], (const float*)d_in[12] };
    float* out = (float*)d_out;

    char* ws = (char*)d_ws;
    size_t OFF_PAIRS = 0;                                     // padded pairs: 4E+4*TOT u32 = 9.6 MB
    size_t OFF_XH    = OFF_PAIRS + ((size_t)4 * NE + 4 * TOT) * 4;  // 23.04 MB fp16 x (slice-major)
    size_t OFF_AGG   = OFF_XH    + NSL * SLB;                 // 92.16 MB fp16 agg
    size_t OFF_CNT   = OFF_AGG   + (size_t)TOT * 768;         // TOT int
    size_t OFF_OFFS  = OFF_CNT   + (size_t)TOT * 4;           // TOT+1 int
    size_t OFF_CUR   = OFF_OFFS  + (size_t)(TOT + 1) * 4;     // TOT int
    size_t OFF_PRE   = OFF_CUR   + (size_t)TOT * 4;           // TOT int
    size_t OFF_BSUM  = OFF_PRE   + (size_t)TOT * 4;           // 128 int
    size_t OFF_BBASE = OFF_BSUM  + (size_t)128 * 4;           // 128 int

    unsigned int* pairs = (unsigned int*)(ws + OFF_PAIRS);
    char*         xh    = ws + OFF_XH;
    char*         agg   = ws + OFF_AGG;
    int* cnt   = (int*)(ws + OFF_CNT);
    int* offs  = (int*)(ws + OFF_OFFS);
    int* cur   = (int*)(ws + OFF_CUR);
    int* pre   = (int*)(ws + OFF_PRE);
    int* bsum  = (int*)(ws + OFF_BSUM);
    int* bbase = (int*)(ws + OFF_BBASE);

    hipMemsetAsync(cnt, 0, (size_t)TOT * 4, stream);

    dim3 eg((NE + 255) / 256, 4);
    hist_kernel<<<eg, 256, 0, stream>>>(ei[0], ei[1], ei[2], ei[3], cnt);
    scanA_kernel<<<NB, 1024, 0, stream>>>(cnt, pre, bsum);
    scanB_kernel<<<1, 128, 0, stream>>>(bsum, bbase, offs);
    scanC_kernel<<<NB, 1024, 0, stream>>>(pre, bbase, offs, cur);
    scatter_kernel<<<eg, 256, 0, stream>>>(ei[0], ei[1], ei[2], ei[3],
                                           ew[0], ew[1], ew[2], ew[3],
                                           cur, pairs);

    conv_kernel<<<(NN * 192 + 255) / 256, 256, 0, stream>>>((const float2*)x, xh);

    dim3 gg(NN / GPB, NSL);
    gather_kernel<<<gg, 256, 0, stream>>>(xh, pairs, offs, cnt, agg);

    matmul_kernel<<<NN / GPM, 384, 0, stream>>>(agg, W[0], W[1], W[2], W[3], bias, out);
}

// Round 11
// 296.330 us; speedup vs baseline: 2.2835x; 1.5485x over previous
//
#include <hip/hip_runtime.h>
#include <hip/hip_fp16.h>

#define NN 30000
#define NE 480000
#define CC 32
#define TT 12
#define CT 384            /* C*T */
#define TOT (4 * NN)      /* 120000 tasks */
#define NB  118           /* ceil(TOT/1024) */
#define NSL 6             /* slices per row */
#define SLB ((size_t)NN * 128)   /* 3.84 MB per 128-B slice array */
#define GPB 8             /* nodes per gather block */
#define GPM 8             /* nodes per matmul block */
#define RSH2 193          /* matmul LDS row stride in half2 (padded) */
#define NBKT 235          /* CSR buckets: 512 rows each */
#define BCAP 16384        /* staging records per bucket (mean 8170, sd ~90) */

typedef unsigned int u32x4 __attribute__((ext_vector_type(4)));
typedef unsigned int u32x2 __attribute__((ext_vector_type(2)));
typedef float f32x2 __attribute__((ext_vector_type(2)));

static __device__ __forceinline__ unsigned int h2u(__half2 h) {
    return __builtin_bit_cast(unsigned int, h);
}
static __device__ __forceinline__ __half2 u2h(unsigned int u) {
    return __builtin_bit_cast(__half2, u);
}

// ---------------- x -> fp16, slice-major (6 slices x 128 B per node row) ----------------

__global__ void conv_kernel(const float2* __restrict__ x2, char* __restrict__ xh) {
    int i = blockIdx.x * blockDim.x + threadIdx.x;
    if (i < NN * 192) {
        float2 v = x2[i];
        int n = i / 192, w = i % 192;            // w = half2 index within row
        __half2* dst = (__half2*)(xh + (size_t)(w >> 5) * SLB);
        dst[n * 32 + (w & 31)] = __floats2half2_rn(v.x, v.y);
    }
}

// ---------------- CSR build: binned, no random global writes ----------------

__global__ void initcur_kernel(int* __restrict__ g_cur) {
    int t = threadIdx.x;
    if (t < NBKT) g_cur[t] = t * BCAP;
}

// pass 1: bin 4096 edges/block into NBKT buckets; contiguous chunk reservation.
__global__ __launch_bounds__(512)
void bin_kernel(const int* __restrict__ ei0, const int* __restrict__ ei1,
                const int* __restrict__ ei2, const int* __restrict__ ei3,
                const float* __restrict__ ew0, const float* __restrict__ ew1,
                const float* __restrict__ ew2, const float* __restrict__ ew3,
                int* __restrict__ g_cur, u32x2* __restrict__ staging) {
    __shared__ int bcnt[NBKT];
    __shared__ int bbase[NBKT];
    const int b = blockIdx.y;
    const int t = threadIdx.x;
    const int e0 = blockIdx.x * 4096;
    const int*   ei = (b == 0) ? ei0 : (b == 1) ? ei1 : (b == 2) ? ei2 : ei3;
    const float* ew = (b == 0) ? ew0 : (b == 1) ? ew1 : (b == 2) ? ew2 : ew3;

    for (int i = t; i < NBKT; i += 512) bcnt[i] = 0;
    __syncthreads();

    int row_[8]; unsigned int pair_[8]; int bkt_[8]; int rank_[8];
#pragma unroll
    for (int i = 0; i < 8; ++i) {
        int e = e0 + i * 512 + t;
        row_[i] = -1;
        if (e < NE) {
            int dst = ei[NE + e];
            int src = ei[e];
            unsigned int w16 = (unsigned int)__half_as_ushort(__float2half_rn(ew[e]));
            row_[i]  = b * NN + dst;
            pair_[i] = (unsigned int)src | (w16 << 16);
            bkt_[i]  = row_[i] >> 9;
            rank_[i] = atomicAdd(&bcnt[bkt_[i]], 1);
        }
    }
    __syncthreads();
    for (int i = t; i < NBKT; i += 512) {
        int cc = bcnt[i];
        bbase[i] = (cc > 0) ? atomicAdd(&g_cur[i], cc) : 0;
    }
    __syncthreads();
#pragma unroll
    for (int i = 0; i < 8; ++i) {
        if (row_[i] >= 0) {
            int pos = bbase[bkt_[i]] + rank_[i];
            if (pos < (bkt_[i] + 1) * BCAP) {      // safety clamp (never in practice)
                u32x2 rec; rec.x = (unsigned int)row_[i]; rec.y = pair_[i];
                staging[pos] = rec;
            }
        }
    }
}

// pass 1.5: per-bucket LDS histogram -> cnt (coalesced writes)
__global__ __launch_bounds__(256)
void count_kernel(const int* __restrict__ g_cur, const u32x2* __restrict__ staging,
                  int* __restrict__ cnt) {
    __shared__ int hist[512];
    const int bkt = blockIdx.x;
    const int t = threadIdx.x;
    hist[t] = 0; hist[t + 256] = 0;
    __syncthreads();
    const int row0 = bkt << 9;
    const int n = g_cur[bkt] - bkt * BCAP;
    const u32x2* __restrict__ sg = staging + (size_t)bkt * BCAP;
    for (int i = t; i < n; i += 256)
        atomicAdd(&hist[(int)sg[i].x - row0], 1);
    __syncthreads();
    if (row0 + t < TOT)       cnt[row0 + t]       = hist[t];
    if (row0 + t + 256 < TOT) cnt[row0 + t + 256] = hist[t + 256];
}

// scans over padded counts
__global__ void scanA_kernel(const int* __restrict__ cnt,
                             int* __restrict__ pre, int* __restrict__ bsum) {
    __shared__ int s[1024];
    int tid = threadIdx.x;
    int i = blockIdx.x * 1024 + tid;
    int v = (i < TOT) ? ((cnt[i] + 3) & ~3) : 0;
    s[tid] = v;
    __syncthreads();
    for (int off = 1; off < 1024; off <<= 1) {
        int t = (tid >= off) ? s[tid - off] : 0;
        __syncthreads();
        s[tid] += t;
        __syncthreads();
    }
    if (i < TOT) pre[i] = s[tid] - v;
    if (tid == 1023) bsum[blockIdx.x] = s[1023];
}

__global__ void scanB_kernel(const int* __restrict__ bsum,
                             int* __restrict__ bbase, int* __restrict__ offs) {
    __shared__ int s[128];
    int tid = threadIdx.x;
    int v = (tid < NB) ? bsum[tid] : 0;
    s[tid] = v;
    __syncthreads();
    for (int off = 1; off < 128; off <<= 1) {
        int t = (tid >= off) ? s[tid - off] : 0;
        __syncthreads();
        s[tid] += t;
        __syncthreads();
    }
    if (tid < NB) bbase[tid] = s[tid] - v;
    if (tid == 127) offs[TOT] = s[127];
}

__global__ void scanC_kernel(const int* __restrict__ pre, const int* __restrict__ bbase,
                             int* __restrict__ offs) {
    int i = blockIdx.x * 1024 + threadIdx.x;
    if (i < TOT) offs[i] = bbase[blockIdx.x] + pre[i];
}

// pass 2: per-bucket sort into final pairs (window-local writes, each line once)
__global__ __launch_bounds__(256)
void sort_kernel(const int* __restrict__ g_cur, const u32x2* __restrict__ staging,
                 const int* __restrict__ offs, unsigned int* __restrict__ pairs) {
    __shared__ int cur[512];
    const int bkt = blockIdx.x;
    const int t = threadIdx.x;
    const int row0 = bkt << 9;
    cur[t]       = (row0 + t < TOT)       ? offs[row0 + t]       : 0;
    cur[t + 256] = (row0 + t + 256 < TOT) ? offs[row0 + t + 256] : 0;
    __syncthreads();
    const int n = g_cur[bkt] - bkt * BCAP;
    const u32x2* __restrict__ sg = staging + (size_t)bkt * BCAP;
    for (int i = t; i < n; i += 256) {
        u32x2 r = sg[i];
        int pos = atomicAdd(&cur[(int)r.x - row0], 1);
        pairs[pos] = r.y;
    }
}

// ---------------- slice-resident gather, octet-per-task, reduction-free ----------------

__global__ __launch_bounds__(256, 8)
void gather_kernel(const char* __restrict__ xh, const unsigned int* __restrict__ pairs,
                   const int* __restrict__ offs, const int* __restrict__ cnt,
                   char* __restrict__ agg) {
    const int tid  = threadIdx.x;
    const int lane = tid & 63;
    const int o = lane >> 3, l = lane & 7;
    const int task = (tid >> 6) * 8 + o;                 // 0..31
    const int node = blockIdx.x * GPB + (task >> 2);
    const int branch = task & 3;
    const int row = branch * NN + node;
    const int slice = blockIdx.y;
    const char* __restrict__ xs = xh + (size_t)slice * SLB + l * 16;

    const int beg = offs[row];
    const int c   = cnt[row];

    __half2 a0 = u2h(0), a1 = u2h(0), a2 = u2h(0), a3 = u2h(0);
    __half2 b0 = u2h(0), b1 = u2h(0), b2 = u2h(0), b3 = u2h(0);

    for (int eb = 0; eb < c; eb += 4) {
        u32x4 pw = *(const u32x4*)(pairs + beg + eb);    // aligned: beg%4==0
#pragma unroll
        for (int u = 0; u < 4; ++u) {
            unsigned int w32 = (u == 0) ? pw.x : (u == 1) ? pw.y : (u == 2) ? pw.z : pw.w;
            if (eb + u < c) {
                u32x4 xv = *(const u32x4*)(xs + (size_t)(w32 & 0xFFFFu) * 128);
                __half2 w2 = __half2half2(__ushort_as_half((unsigned short)(w32 >> 16)));
                if (u & 1) {
                    b0 = __hfma2(w2, u2h(xv.x), b0);
                    b1 = __hfma2(w2, u2h(xv.y), b1);
                    b2 = __hfma2(w2, u2h(xv.z), b2);
                    b3 = __hfma2(w2, u2h(xv.w), b3);
                } else {
                    a0 = __hfma2(w2, u2h(xv.x), a0);
                    a1 = __hfma2(w2, u2h(xv.y), a1);
                    a2 = __hfma2(w2, u2h(xv.z), a2);
                    a3 = __hfma2(w2, u2h(xv.w), a3);
                }
            }
        }
    }
    u32x4 r;
    r.x = h2u(__hadd2(a0, b0));
    r.y = h2u(__hadd2(a1, b1));
    r.z = h2u(__hadd2(a2, b2));
    r.w = h2u(__hadd2(a3, b3));
    __builtin_nontemporal_store(r, (u32x4*)(agg + (size_t)row * 768 + slice * 128 + l * 16));
}

// ---------------- streaming matmul: out = bias + sum_b agg_b @ W_b ----------------

__global__ __launch_bounds__(384)
void matmul_kernel(const char* __restrict__ agg,
                   const float* __restrict__ W0, const float* __restrict__ W1,
                   const float* __restrict__ W2, const float* __restrict__ W3,
                   const float* __restrict__ bias, float* __restrict__ out) {
    __shared__ __half2 aggB[32 * RSH2];   // ~24.7 KB
    const int tid = threadIdx.x;
    const int n0 = blockIdx.x * GPM;

    {
        const int r = tid / 12, sub = tid % 12;
        const char* src = agg + (size_t)((r & 3) * NN + n0 + (r >> 2)) * 768 + sub * 64;
        char* dst = (char*)(aggB + r * RSH2) + sub * 64;
#pragma unroll
        for (int q = 0; q < 4; ++q) {
            u32x4 v = __builtin_nontemporal_load((const u32x4*)(src + 16 * q));
            *(u32x4*)(dst + 16 * q) = v;
        }
    }
    __syncthreads();

    const float* Ws[4] = { W0, W1, W2, W3 };
    {
        const int g = tid / 48;
        const int rem = tid % 48;
        const int q = rem / 6;
        const int t2 = rem % 6;
        f32x2 acc[4];
#pragma unroll
        for (int i = 0; i < 4; ++i) { float bv = bias[q * 4 + i]; acc[i].x = bv; acc[i].y = bv; }
#pragma unroll
        for (int b = 0; b < 4; ++b) {
            const float* __restrict__ Wb = Ws[b];
            const __half2* __restrict__ aL = aggB + (g * 4 + b) * RSH2 + t2;
#pragma unroll
            for (int h = 0; h < 2; ++h) {
                float2 row[16];
#pragma unroll
                for (int kk = 0; kk < 16; ++kk)
                    row[kk] = __half22float2(aL[(h * 16 + kk) * 6]);
#pragma unroll
                for (int kk = 0; kk < 16; ++kk) {
#pragma unroll
                    for (int i = 0; i < 4; ++i) {
                        float w = Wb[(h * 16 + kk) * CC + q * 4 + i];
                        acc[i].x = fmaf(w, row[kk].x, acc[i].x);
                        acc[i].y = fmaf(w, row[kk].y, acc[i].y);
                    }
                }
            }
        }
#pragma unroll
        for (int i = 0; i < 4; ++i) {
            f32x2* dst = (f32x2*)&out[(size_t)(n0 + g) * CT + (q * 4 + i) * TT + 2 * t2];
            __builtin_nontemporal_store(acc[i], dst);
        }
    }
}

// ---------------- launch ----------------

extern "C" void kernel_launch(void* const* d_in, const int* in_sizes, int n_in,
                              void* d_out, int out_size, void* d_ws, size_t ws_size,
                              hipStream_t stream) {
    const float* x    = (const float*)d_in[0];
    const float* bias = (const float*)d_in[13];
    const int*   ei[4] = { (const int*)d_in[1], (const int*)d_in[4],
                           (const int*)d_in[7], (const int*)d_in[10] };
    const float* ew[4] = { (const float*)d_in[2], (const float*)d_in[5],
                           (const float*)d_in[8], (const float*)d_in[11] };
    const float* W[4]  = { (const float*)d_in[3], (const float*)d_in[6],
                           (const float*)d_in[9], (const float*)d_in[12] };
    float* out = (float*)d_out;

    char* ws = (char*)d_ws;
    size_t OFF_PAIRS = 0;                                     // padded pairs: 9.6 MB
    size_t OFF_XH    = OFF_PAIRS + ((size_t)4 * NE + 4 * TOT) * 4;  // 23.04 MB fp16 x
    size_t OFF_AGG   = OFF_XH    + NSL * SLB;                 // 92.16 MB agg (staging overlay)
    size_t OFF_CNT   = OFF_AGG   + (size_t)TOT * 768;         // TOT int
    size_t OFF_OFFS  = OFF_CNT   + (size_t)TOT * 4;           // TOT+1 int
    size_t OFF_PRE   = OFF_OFFS  + (size_t)(TOT + 1) * 4;     // TOT int
    size_t OFF_BSUM  = OFF_PRE   + (size_t)TOT * 4;           // 128 int
    size_t OFF_BBASE = OFF_BSUM  + (size_t)128 * 4;           // 128 int
    size_t OFF_GCUR  = OFF_BBASE + (size_t)128 * 4;           // NBKT int

    unsigned int* pairs = (unsigned int*)(ws + OFF_PAIRS);
    char*         xh    = ws + OFF_XH;
    char*         agg   = ws + OFF_AGG;
    u32x2*        staging = (u32x2*)(ws + OFF_AGG);           // overlay: dead before gather
    int* cnt   = (int*)(ws + OFF_CNT);
    int* offs  = (int*)(ws + OFF_OFFS);
    int* pre   = (int*)(ws + OFF_PRE);
    int* bsum  = (int*)(ws + OFF_BSUM);
    int* bbase = (int*)(ws + OFF_BBASE);
    int* g_cur = (int*)(ws + OFF_GCUR);

    initcur_kernel<<<1, 256, 0, stream>>>(g_cur);

    dim3 bg((NE + 4095) / 4096, 4);
    bin_kernel<<<bg, 512, 0, stream>>>(ei[0], ei[1], ei[2], ei[3],
                                       ew[0], ew[1], ew[2], ew[3],
                                       g_cur, staging);
    count_kernel<<<NBKT, 256, 0, stream>>>(g_cur, staging, cnt);
    scanA_kernel<<<NB, 1024, 0, stream>>>(cnt, pre, bsum);
    scanB_kernel<<<1, 128, 0, stream>>>(bsum, bbase, offs);
    scanC_kernel<<<NB, 1024, 0, stream>>>(pre, bbase, offs);
    sort_kernel<<<NBKT, 256, 0, stream>>>(g_cur, staging, offs, pairs);

    conv_kernel<<<(NN * 192 + 255) / 256, 256, 0, stream>>>((const float2*)x, xh);

    dim3 gg(NN / GPB, NSL);
    gather_kernel<<<gg, 256, 0, stream>>>(xh, pairs, offs, cnt, agg);

    matmul_kernel<<<NN / GPM, 384, 0, stream>>>(agg, W[0], W[1], W[2], W[3], bias, out);
}